// Round 5
// baseline (572.326 us; speedup 1.0000x reference)
//
#include <hip/hip_runtime.h>

#define N_NODES 100000
#define N_EDGES 1000000
#define N_GRAPHS 128
#define IN_DIM 32
#define HID 64
#define LAT 32
#define N_LAYERS 3

#define MPAD 68  // padded LDS row stride (floats), 16B-aligned rows
#define NB_SUM ((N_NODES + 255) / 256)  // 391 scan blocks

// bf16 <-> fp32 helpers (storage-only bf16; all math fp32)
__device__ __forceinline__ float bf2f(unsigned short u) {
    return __uint_as_float(((unsigned int)u) << 16);
}
__device__ __forceinline__ unsigned short f2bf(float f) {
    unsigned int x = __float_as_uint(f);
    x += 0x7fffu + ((x >> 16) & 1u);  // round-to-nearest-even
    return (unsigned short)(x >> 16);
}

// ---------------- input projection: h = bf16(x @ w_in + b_in) ----------------
__global__ __launch_bounds__(256) void proj_kernel(
    const float* __restrict__ x, const float* __restrict__ w_in,
    const float* __restrict__ b_in, unsigned short* __restrict__ h) {
    __shared__ float ws[IN_DIM * HID];   // 8 KB
    __shared__ float xs[4 * IN_DIM];
    int tid = threadIdx.x;
    for (int i = tid; i < IN_DIM * HID / 4; i += 256)
        ((float4*)ws)[i] = ((const float4*)w_in)[i];
    if (tid < 32) {
        int r = tid >> 3, c4 = tid & 7;
        int nn = blockIdx.x * 4 + r;
        float4 v = make_float4(0.f, 0.f, 0.f, 0.f);
        if (nn < N_NODES) v = ((const float4*)(x + (size_t)nn * IN_DIM))[c4];
        ((float4*)xs)[tid] = v;
    }
    __syncthreads();
    int w = tid >> 6, j = tid & 63;
    int n = blockIdx.x * 4 + w;
    if (n >= N_NODES) return;
    float acc = b_in[j];
#pragma unroll
    for (int k = 0; k < IN_DIM; k += 4) {
        float4 xv = *(const float4*)&xs[w * IN_DIM + k];
        acc += xv.x * ws[(k + 0) * HID + j];
        acc += xv.y * ws[(k + 1) * HID + j];
        acc += xv.z * ws[(k + 2) * HID + j];
        acc += xv.w * ws[(k + 3) * HID + j];
    }
    h[(size_t)n * HID + j] = f2bf(acc);
}

// ---------------- CSR build ----------------
__global__ __launch_bounds__(256) void hist_kernel(const int* __restrict__ ei,
                                                   int* __restrict__ counts) {
    int e = blockIdx.x * 256 + threadIdx.x;
    if (e < N_EDGES) atomicAdd(&counts[ei[N_EDGES + e]], 1);
}

__global__ __launch_bounds__(256) void block_sum_kernel(
    const int* __restrict__ counts, int* __restrict__ bsums) {
    __shared__ int sd[4];
    int i = blockIdx.x * 256 + threadIdx.x;
    int v = (i < N_NODES) ? counts[i] : 0;
#pragma unroll
    for (int off = 32; off >= 1; off >>= 1) v += __shfl_down(v, off);
    int lane = threadIdx.x & 63, w = threadIdx.x >> 6;
    if (lane == 0) sd[w] = v;
    __syncthreads();
    if (threadIdx.x == 0) bsums[blockIdx.x] = sd[0] + sd[1] + sd[2] + sd[3];
}

__global__ __launch_bounds__(256) void scan_bsums_kernel(
    const int* __restrict__ bsums, int* __restrict__ bofs, int nb) {
    __shared__ int tmp[256];
    __shared__ int carry;
    int tid = threadIdx.x;
    if (tid == 0) carry = 0;
    __syncthreads();
    for (int base = 0; base < nb; base += 256) {
        int v = (base + tid < nb) ? bsums[base + tid] : 0;
        tmp[tid] = v;
        __syncthreads();
        for (int off = 1; off < 256; off <<= 1) {
            int t = (tid >= off) ? tmp[tid - off] : 0;
            __syncthreads();
            tmp[tid] += t;
            __syncthreads();
        }
        if (base + tid < nb) bofs[base + tid] = carry + tmp[tid] - v;
        __syncthreads();
        if (tid == 255) carry += tmp[255];
        __syncthreads();
    }
}

__global__ __launch_bounds__(256) void offsets_kernel(
    const int* __restrict__ counts, const int* __restrict__ bofs,
    int* __restrict__ offsets, int* __restrict__ cursor) {
    __shared__ int tmp[256];
    int tid = threadIdx.x;
    int i = blockIdx.x * 256 + tid;
    int v = (i < N_NODES) ? counts[i] : 0;
    tmp[tid] = v;
    __syncthreads();
    for (int off = 1; off < 256; off <<= 1) {
        int t = (tid >= off) ? tmp[tid - off] : 0;
        __syncthreads();
        tmp[tid] += t;
        __syncthreads();
    }
    int excl = tmp[tid] - v + bofs[blockIdx.x];
    if (i < N_NODES) {
        offsets[i] = excl;
        cursor[i] = excl;
        if (i == N_NODES - 1) offsets[N_NODES] = excl + v;
    }
}

__global__ __launch_bounds__(256) void fill_kernel(const int* __restrict__ ei,
                                                   int* __restrict__ cursor,
                                                   int* __restrict__ srcs) {
    int e = blockIdx.x * 256 + threadIdx.x;
    if (e < N_EDGES) {
        int d = ei[N_EDGES + e];
        int s = ei[e];
        int p = atomicAdd(&cursor[d], 1);
        __builtin_nontemporal_store(s, &srcs[p]);  // write-once, read much later
    }
}

// ---------------- fused layer: gather + GIN MLP (bf16 h storage) -----------
// block = 64 nodes, 512 threads (8 waves). Phase 1: wave w gathers rows
// [w*8, w*8+8): lane j = feature j, edge ids shfl-broadcast, 4 ILP chains;
// m = h_in + agg written to LDS (fp32). Phase 2: two 64x64 GEMMs, 2x4
// micro-tile. Epilogue: h_out = bf16(relu(.) + h_in).
// NOTE: no min-waves launch_bounds clause (R3: it forced spills -> 1.5 GB scratch).
__global__ __launch_bounds__(512) void layer_kernel(
    const unsigned short* __restrict__ h_in, unsigned short* __restrict__ h_out,
    const int* __restrict__ offsets, const int* __restrict__ srcs,
    const float* __restrict__ w1, const float* __restrict__ b1,
    const float* __restrict__ w2, const float* __restrict__ b2) {
    __shared__ float w1s[HID * HID];   // 16 KB
    __shared__ float w2s[HID * HID];   // 16 KB
    __shared__ float ms[64 * MPAD];    // 17 KB, reused for t
    int tid = threadIdx.x;
    int row0 = blockIdx.x * 64;
    for (int i = tid; i < HID * HID / 4; i += 512) {
        ((float4*)w1s)[i] = ((const float4*)w1)[i];
        ((float4*)w2s)[i] = ((const float4*)w2)[i];
    }

    // ---- gather phase ----
    int w = tid >> 6, j = tid & 63;
    for (int r = w * 8; r < w * 8 + 8; r++) {
        int n = row0 + r;
        float acc0 = 0.f, acc1 = 0.f, acc2 = 0.f, acc3 = 0.f;
        if (n < N_NODES) {
            int beg = offsets[n], end = offsets[n + 1];
            for (int c = beg; c < end; c += 64) {
                int myS = (c + j < end) ? srcs[c + j] : 0;
                int m = min(64, end - c);
                int i2 = 0;
                for (; i2 + 3 < m; i2 += 4) {
                    int s0 = __shfl(myS, i2);
                    int s1 = __shfl(myS, i2 + 1);
                    int s2 = __shfl(myS, i2 + 2);
                    int s3 = __shfl(myS, i2 + 3);
                    acc0 += bf2f(h_in[(size_t)s0 * HID + j]);
                    acc1 += bf2f(h_in[(size_t)s1 * HID + j]);
                    acc2 += bf2f(h_in[(size_t)s2 * HID + j]);
                    acc3 += bf2f(h_in[(size_t)s3 * HID + j]);
                }
                for (; i2 < m; i2++)
                    acc0 += bf2f(h_in[(size_t)__shfl(myS, i2) * HID + j]);
            }
            acc0 += acc1 + acc2 + acc3 + bf2f(h_in[(size_t)n * HID + j]);
        }
        ms[r * MPAD + j] = acc0;
    }
    __syncthreads();

    // ---- GEMM phase: ty 0..31 (2 rows), tx 0..15 (4 cols) ----
    int ty = tid >> 4, tx = tid & 15;
    int r0 = ty * 2, c0 = tx * 4;

    float4 a0, a1;
#define GEMM_LDS(WS)                                                          \
    do {                                                                      \
        a0 = make_float4(0.f, 0.f, 0.f, 0.f); a1 = a0;                        \
        _Pragma("unroll 4")                                                   \
        for (int k0 = 0; k0 < HID; k0 += 4) {                                 \
            float4 m0 = *(const float4*)&ms[(r0 + 0) * MPAD + k0];            \
            float4 m1 = *(const float4*)&ms[(r0 + 1) * MPAD + k0];            \
            float4 w0 = *(const float4*)&WS[(k0 + 0) * HID + c0];             \
            float4 w1v = *(const float4*)&WS[(k0 + 1) * HID + c0];            \
            float4 w2v = *(const float4*)&WS[(k0 + 2) * HID + c0];            \
            float4 w3v = *(const float4*)&WS[(k0 + 3) * HID + c0];            \
            a0.x += m0.x * w0.x + m0.y * w1v.x + m0.z * w2v.x + m0.w * w3v.x; \
            a0.y += m0.x * w0.y + m0.y * w1v.y + m0.z * w2v.y + m0.w * w3v.y; \
            a0.z += m0.x * w0.z + m0.y * w1v.z + m0.z * w2v.z + m0.w * w3v.z; \
            a0.w += m0.x * w0.w + m0.y * w1v.w + m0.z * w2v.w + m0.w * w3v.w; \
            a1.x += m1.x * w0.x + m1.y * w1v.x + m1.z * w2v.x + m1.w * w3v.x; \
            a1.y += m1.x * w0.y + m1.y * w1v.y + m1.z * w2v.y + m1.w * w3v.y; \
            a1.z += m1.x * w0.z + m1.y * w1v.z + m1.z * w2v.z + m1.w * w3v.z; \
            a1.w += m1.x * w0.w + m1.y * w1v.w + m1.z * w2v.w + m1.w * w3v.w; \
        }                                                                     \
    } while (0)

    GEMM_LDS(w1s);  // GEMM1

    float4 bv1 = *(const float4*)&b1[c0];
    float4 t0 = make_float4(fmaxf(a0.x + bv1.x, 0.f), fmaxf(a0.y + bv1.y, 0.f),
                            fmaxf(a0.z + bv1.z, 0.f), fmaxf(a0.w + bv1.w, 0.f));
    float4 t1 = make_float4(fmaxf(a1.x + bv1.x, 0.f), fmaxf(a1.y + bv1.y, 0.f),
                            fmaxf(a1.z + bv1.z, 0.f), fmaxf(a1.w + bv1.w, 0.f));

    __syncthreads();  // all GEMM1 reads of ms complete
    *(float4*)&ms[(r0 + 0) * MPAD + c0] = t0;
    *(float4*)&ms[(r0 + 1) * MPAD + c0] = t1;
    __syncthreads();

    GEMM_LDS(w2s);  // GEMM2

    float4 bv2 = *(const float4*)&b2[c0];
#pragma unroll
    for (int i = 0; i < 2; i++) {
        int n = row0 + r0 + i;
        if (n < N_NODES) {
            float4 av = (i == 0) ? a0 : a1;
            // skip connection: re-read h_in row (bf16, L2-hot)
            const unsigned short* hp = h_in + (size_t)n * HID + c0;
            float o0 = fmaxf(av.x + bv2.x, 0.f) + bf2f(hp[0]);
            float o1 = fmaxf(av.y + bv2.y, 0.f) + bf2f(hp[1]);
            float o2 = fmaxf(av.z + bv2.z, 0.f) + bf2f(hp[2]);
            float o3 = fmaxf(av.w + bv2.w, 0.f) + bf2f(hp[3]);
            uint2 pk;
            pk.x = (unsigned int)f2bf(o0) | ((unsigned int)f2bf(o1) << 16);
            pk.y = (unsigned int)f2bf(o2) | ((unsigned int)f2bf(o3) << 16);
            *(uint2*)(h_out + (size_t)n * HID + c0) = pk;
        }
    }
#undef GEMM_LDS
}

// ---------------- global add pool (bf16 h) ----------------
__global__ __launch_bounds__(256) void pool_kernel(
    const unsigned short* __restrict__ h, const int* __restrict__ batch,
    float* __restrict__ pooled) {
    int tid = threadIdx.x;
    int w = tid >> 6, j = tid & 63;
    int n0 = blockIdx.x * 256 + w * 64;
    if (n0 >= N_NODES) return;
    int nend = min(n0 + 64, N_NODES);
    float acc = 0.f;
    int cur = batch[n0];
    for (int n = n0; n < nend; n++) {
        int b = batch[n];
        if (b != cur) {
            atomicAdd(&pooled[cur * HID + j], acc);
            acc = 0.f;
            cur = b;
        }
        acc += bf2f(h[(size_t)n * HID + j]);
    }
    atomicAdd(&pooled[cur * HID + j], acc);
}

// ---------------- final FC ----------------
__global__ __launch_bounds__(256) void final_kernel(
    const float* __restrict__ pooled, const float* __restrict__ w_fc,
    const float* __restrict__ b_fc, float* __restrict__ out) {
    int gid = blockIdx.x * 256 + threadIdx.x;
    if (gid >= N_GRAPHS * LAT) return;
    int g = gid >> 5, j = gid & 31;
    float acc = b_fc[j];
#pragma unroll
    for (int k = 0; k < HID; k++)
        acc += pooled[g * HID + k] * w_fc[k * LAT + j];
    out[gid] = acc;
}

extern "C" void kernel_launch(void* const* d_in, const int* in_sizes, int n_in,
                              void* d_out, int out_size, void* d_ws,
                              size_t ws_size, hipStream_t stream) {
    const float* x     = (const float*)d_in[0];
    const int*   ei    = (const int*)d_in[1];
    const int*   batch = (const int*)d_in[2];
    const float* w_in  = (const float*)d_in[3];
    const float* b_in  = (const float*)d_in[4];
    const float* w1    = (const float*)d_in[5];
    const float* b1    = (const float*)d_in[6];
    const float* w2    = (const float*)d_in[7];
    const float* b2    = (const float*)d_in[8];
    const float* w_fc  = (const float*)d_in[9];
    const float* b_fc  = (const float*)d_in[10];
    float* out = (float*)d_out;

    // persistent: h0 | h1 (bf16, 12.8 MB each) | pooled | offsets | srcs (~30 MB)
    unsigned short* h0 = (unsigned short*)d_ws;
    unsigned short* h1 = h0 + (size_t)N_NODES * HID;
    float* pooled  = (float*)(h1 + (size_t)N_NODES * HID);
    int*   offsets = (int*)(pooled + N_GRAPHS * HID);   // N_NODES+1
    int*   srcs    = offsets + (N_NODES + 2);           // N_EDGES
    // CSR build scratch overlaid into h1 (dead before layer 0 writes h1)
    int* counts = (int*)h1;             // N_NODES
    int* cursor = counts + N_NODES;     // N_NODES
    int* bsums  = cursor + N_NODES;     // NB_SUM
    int* bofs   = bsums + (NB_SUM + 1); // NB_SUM

    proj_kernel<<<(N_NODES + 3) / 4, 256, 0, stream>>>(x, w_in, b_in, h0);

    // CSR build (once; edges constant across layers)
    hipMemsetAsync(counts, 0, N_NODES * sizeof(int), stream);
    hist_kernel<<<(N_EDGES + 255) / 256, 256, 0, stream>>>(ei, counts);
    block_sum_kernel<<<NB_SUM, 256, 0, stream>>>(counts, bsums);
    scan_bsums_kernel<<<1, 256, 0, stream>>>(bsums, bofs, NB_SUM);
    offsets_kernel<<<NB_SUM, 256, 0, stream>>>(counts, bofs, offsets, cursor);
    fill_kernel<<<(N_EDGES + 255) / 256, 256, 0, stream>>>(ei, cursor, srcs);

    // fused layers, h double-buffered: h0->h1->h0->h1
    const unsigned short* hin = h0;
    unsigned short* hout = h1;
    for (int i = 0; i < N_LAYERS; i++) {
        layer_kernel<<<(N_NODES + 63) / 64, 512, 0, stream>>>(
            hin, hout, offsets, srcs,
            w1 + (size_t)i * HID * HID, b1 + (size_t)i * HID,
            w2 + (size_t)i * HID * HID, b2 + (size_t)i * HID);
        const unsigned short* tmp = hout;
        hout = (unsigned short*)hin;
        hin = tmp;
    }

    hipMemsetAsync(pooled, 0, N_GRAPHS * HID * sizeof(float), stream);
    pool_kernel<<<(N_NODES + 255) / 256, 256, 0, stream>>>(hin, batch, pooled);
    final_kernel<<<(N_GRAPHS * LAT + 255) / 256, 256, 0, stream>>>(
        pooled, w_fc, b_fc, out);
}

// Round 6
// 531.472 us; speedup vs baseline: 1.0769x; 1.0769x over previous
//
#include <hip/hip_runtime.h>

#define N_NODES 100000
#define N_EDGES 1000000
#define N_GRAPHS 128
#define IN_DIM 32
#define HID 64
#define LAT 32
#define N_LAYERS 3

#define MPAD 68  // padded LDS row stride (floats), 16B-aligned rows
#define NB_SUM ((N_NODES + 255) / 256)  // 391 scan blocks

// bf16 <-> fp32 helpers (storage-only bf16; all math fp32)
__device__ __forceinline__ float bf2f(unsigned short u) {
    return __uint_as_float(((unsigned int)u) << 16);
}
__device__ __forceinline__ unsigned short f2bf(float f) {
    unsigned int x = __float_as_uint(f);
    x += 0x7fffu + ((x >> 16) & 1u);  // round-to-nearest-even
    return (unsigned short)(x >> 16);
}

// ---------------- input projection: h = bf16(x @ w_in + b_in) ----------------
__global__ __launch_bounds__(256) void proj_kernel(
    const float* __restrict__ x, const float* __restrict__ w_in,
    const float* __restrict__ b_in, unsigned short* __restrict__ h) {
    __shared__ float ws[IN_DIM * HID];   // 8 KB
    __shared__ float xs[4 * IN_DIM];
    int tid = threadIdx.x;
    for (int i = tid; i < IN_DIM * HID / 4; i += 256)
        ((float4*)ws)[i] = ((const float4*)w_in)[i];
    if (tid < 32) {
        int r = tid >> 3, c4 = tid & 7;
        int nn = blockIdx.x * 4 + r;
        float4 v = make_float4(0.f, 0.f, 0.f, 0.f);
        if (nn < N_NODES) v = ((const float4*)(x + (size_t)nn * IN_DIM))[c4];
        ((float4*)xs)[tid] = v;
    }
    __syncthreads();
    int w = tid >> 6, j = tid & 63;
    int n = blockIdx.x * 4 + w;
    if (n >= N_NODES) return;
    float acc = b_in[j];
#pragma unroll
    for (int k = 0; k < IN_DIM; k += 4) {
        float4 xv = *(const float4*)&xs[w * IN_DIM + k];
        acc += xv.x * ws[(k + 0) * HID + j];
        acc += xv.y * ws[(k + 1) * HID + j];
        acc += xv.z * ws[(k + 2) * HID + j];
        acc += xv.w * ws[(k + 3) * HID + j];
    }
    h[(size_t)n * HID + j] = f2bf(acc);
}

// ---------------- CSR build ----------------
__global__ __launch_bounds__(256) void hist_kernel(const int* __restrict__ ei,
                                                   int* __restrict__ counts) {
    int e = blockIdx.x * 256 + threadIdx.x;
    if (e < N_EDGES) atomicAdd(&counts[ei[N_EDGES + e]], 1);
}

__global__ __launch_bounds__(256) void block_sum_kernel(
    const int* __restrict__ counts, int* __restrict__ bsums) {
    __shared__ int sd[4];
    int i = blockIdx.x * 256 + threadIdx.x;
    int v = (i < N_NODES) ? counts[i] : 0;
#pragma unroll
    for (int off = 32; off >= 1; off >>= 1) v += __shfl_down(v, off);
    int lane = threadIdx.x & 63, w = threadIdx.x >> 6;
    if (lane == 0) sd[w] = v;
    __syncthreads();
    if (threadIdx.x == 0) bsums[blockIdx.x] = sd[0] + sd[1] + sd[2] + sd[3];
}

__global__ __launch_bounds__(256) void scan_bsums_kernel(
    const int* __restrict__ bsums, int* __restrict__ bofs, int nb) {
    __shared__ int tmp[256];
    __shared__ int carry;
    int tid = threadIdx.x;
    if (tid == 0) carry = 0;
    __syncthreads();
    for (int base = 0; base < nb; base += 256) {
        int v = (base + tid < nb) ? bsums[base + tid] : 0;
        tmp[tid] = v;
        __syncthreads();
        for (int off = 1; off < 256; off <<= 1) {
            int t = (tid >= off) ? tmp[tid - off] : 0;
            __syncthreads();
            tmp[tid] += t;
            __syncthreads();
        }
        if (base + tid < nb) bofs[base + tid] = carry + tmp[tid] - v;
        __syncthreads();
        if (tid == 255) carry += tmp[255];
        __syncthreads();
    }
}

__global__ __launch_bounds__(256) void offsets_kernel(
    const int* __restrict__ counts, const int* __restrict__ bofs,
    int* __restrict__ offsets, int* __restrict__ cursor) {
    __shared__ int tmp[256];
    int tid = threadIdx.x;
    int i = blockIdx.x * 256 + tid;
    int v = (i < N_NODES) ? counts[i] : 0;
    tmp[tid] = v;
    __syncthreads();
    for (int off = 1; off < 256; off <<= 1) {
        int t = (tid >= off) ? tmp[tid - off] : 0;
        __syncthreads();
        tmp[tid] += t;
        __syncthreads();
    }
    int excl = tmp[tid] - v + bofs[blockIdx.x];
    if (i < N_NODES) {
        offsets[i] = excl;
        cursor[i] = excl;
        if (i == N_NODES - 1) offsets[N_NODES] = excl + v;
    }
}

// plain store (R5 lesson: nontemporal scatter bypasses L2 write-combining -> ~2x slower)
__global__ __launch_bounds__(256) void fill_kernel(const int* __restrict__ ei,
                                                   int* __restrict__ cursor,
                                                   int* __restrict__ srcs) {
    int e = blockIdx.x * 256 + threadIdx.x;
    if (e < N_EDGES) {
        int d = ei[N_EDGES + e];
        int p = atomicAdd(&cursor[d], 1);
        srcs[p] = ei[e];
    }
}

// ---------------- fused layer: gather + GIN MLP (bf16 h storage) -----------
// block = 64 nodes, 512 threads (8 waves). Gather: wave w owns rows
// [w*8, w*8+8); quarter-wave q (16 lanes) handles edge slot q; each lane
// loads uint2 = 4 bf16 feats (8B, coalesced 128B/row). 2 chains -> 8 edges
// in flight/wave. Cross-quarter shfl_xor reduce, lanes q==0 write LDS.
// GEMM: two 64x64 through LDS, 2x4 micro-tile. No min-waves clause (R3).
__global__ __launch_bounds__(512) void layer_kernel(
    const unsigned short* __restrict__ h_in, unsigned short* __restrict__ h_out,
    const int* __restrict__ offsets, const int* __restrict__ srcs,
    const float* __restrict__ w1, const float* __restrict__ b1,
    const float* __restrict__ w2, const float* __restrict__ b2) {
    __shared__ float w1s[HID * HID];   // 16 KB
    __shared__ float w2s[HID * HID];   // 16 KB
    __shared__ float ms[64 * MPAD];    // 17 KB, reused for t
    int tid = threadIdx.x;
    int row0 = blockIdx.x * 64;
    for (int i = tid; i < HID * HID / 4; i += 512) {
        ((float4*)w1s)[i] = ((const float4*)w1)[i];
        ((float4*)w2s)[i] = ((const float4*)w2)[i];
    }

    // ---- gather phase ----
    int w = tid >> 6, j = tid & 63;
    int q = j >> 4;          // edge slot 0..3
    int fl = j & 15;         // feature-quad index (feats fl*4 .. fl*4+3)
#define UNPACK_ADD(A, V)                            \
    do {                                            \
        (A).x += __uint_as_float((V).x << 16);      \
        (A).y += __uint_as_float((V).x & 0xffff0000u); \
        (A).z += __uint_as_float((V).y << 16);      \
        (A).w += __uint_as_float((V).y & 0xffff0000u); \
    } while (0)

    for (int r = w * 8; r < w * 8 + 8; r++) {
        int n = row0 + r;
        float4 acc = make_float4(0.f, 0.f, 0.f, 0.f), acc2 = acc;
        if (n < N_NODES) {
            int beg = offsets[n], end = offsets[n + 1];
            for (int c = beg; c < end; c += 64) {
                int myS = (c + j < end) ? srcs[c + j] : 0;
                int m = min(64, end - c);
                int i2 = 0;
                for (; i2 + 7 < m; i2 += 8) {
                    int sA = __shfl(myS, i2 + q);
                    int sB = __shfl(myS, i2 + 4 + q);
                    uint2 va = *(const uint2*)(h_in + (size_t)sA * HID + (fl << 2));
                    uint2 vb = *(const uint2*)(h_in + (size_t)sB * HID + (fl << 2));
                    UNPACK_ADD(acc, va);
                    UNPACK_ADD(acc2, vb);
                }
                for (; i2 < m; i2 += 4) {
                    int idx = i2 + q;
                    if (idx < m) {
                        int s = __shfl(myS, idx);
                        uint2 v = *(const uint2*)(h_in + (size_t)s * HID + (fl << 2));
                        UNPACK_ADD(acc, v);
                    }
                }
            }
            if (q == 0) {  // self term: m = agg + h (eps=0), added once
                uint2 v = *(const uint2*)(h_in + (size_t)n * HID + (fl << 2));
                UNPACK_ADD(acc, v);
            }
        }
        acc.x += acc2.x; acc.y += acc2.y; acc.z += acc2.z; acc.w += acc2.w;
        // cross-quarter reduce (lanes j, j^16, j^32, j^48 share feature quad)
        acc.x += __shfl_xor(acc.x, 16); acc.y += __shfl_xor(acc.y, 16);
        acc.z += __shfl_xor(acc.z, 16); acc.w += __shfl_xor(acc.w, 16);
        acc.x += __shfl_xor(acc.x, 32); acc.y += __shfl_xor(acc.y, 32);
        acc.z += __shfl_xor(acc.z, 32); acc.w += __shfl_xor(acc.w, 32);
        if (q == 0) *(float4*)&ms[r * MPAD + (fl << 2)] = acc;
    }
#undef UNPACK_ADD
    __syncthreads();

    // ---- GEMM phase: ty 0..31 (2 rows), tx 0..15 (4 cols) ----
    int ty = tid >> 4, tx = tid & 15;
    int r0 = ty * 2, c0 = tx * 4;

    float4 a0, a1;
#define GEMM_LDS(WS)                                                          \
    do {                                                                      \
        a0 = make_float4(0.f, 0.f, 0.f, 0.f); a1 = a0;                        \
        _Pragma("unroll 4")                                                   \
        for (int k0 = 0; k0 < HID; k0 += 4) {                                 \
            float4 m0 = *(const float4*)&ms[(r0 + 0) * MPAD + k0];            \
            float4 m1 = *(const float4*)&ms[(r0 + 1) * MPAD + k0];            \
            float4 w0 = *(const float4*)&WS[(k0 + 0) * HID + c0];             \
            float4 w1v = *(const float4*)&WS[(k0 + 1) * HID + c0];            \
            float4 w2v = *(const float4*)&WS[(k0 + 2) * HID + c0];            \
            float4 w3v = *(const float4*)&WS[(k0 + 3) * HID + c0];            \
            a0.x += m0.x * w0.x + m0.y * w1v.x + m0.z * w2v.x + m0.w * w3v.x; \
            a0.y += m0.x * w0.y + m0.y * w1v.y + m0.z * w2v.y + m0.w * w3v.y; \
            a0.z += m0.x * w0.z + m0.y * w1v.z + m0.z * w2v.z + m0.w * w3v.z; \
            a0.w += m0.x * w0.w + m0.y * w1v.w + m0.z * w2v.w + m0.w * w3v.w; \
            a1.x += m1.x * w0.x + m1.y * w1v.x + m1.z * w2v.x + m1.w * w3v.x; \
            a1.y += m1.x * w0.y + m1.y * w1v.y + m1.z * w2v.y + m1.w * w3v.y; \
            a1.z += m1.x * w0.z + m1.y * w1v.z + m1.z * w2v.z + m1.w * w3v.z; \
            a1.w += m1.x * w0.w + m1.y * w1v.w + m1.z * w2v.w + m1.w * w3v.w; \
        }                                                                     \
    } while (0)

    GEMM_LDS(w1s);  // GEMM1

    float4 bv1 = *(const float4*)&b1[c0];
    float4 t0 = make_float4(fmaxf(a0.x + bv1.x, 0.f), fmaxf(a0.y + bv1.y, 0.f),
                            fmaxf(a0.z + bv1.z, 0.f), fmaxf(a0.w + bv1.w, 0.f));
    float4 t1 = make_float4(fmaxf(a1.x + bv1.x, 0.f), fmaxf(a1.y + bv1.y, 0.f),
                            fmaxf(a1.z + bv1.z, 0.f), fmaxf(a1.w + bv1.w, 0.f));

    __syncthreads();  // all GEMM1 reads of ms complete
    *(float4*)&ms[(r0 + 0) * MPAD + c0] = t0;
    *(float4*)&ms[(r0 + 1) * MPAD + c0] = t1;
    __syncthreads();

    GEMM_LDS(w2s);  // GEMM2

    float4 bv2 = *(const float4*)&b2[c0];
#pragma unroll
    for (int i = 0; i < 2; i++) {
        int n = row0 + r0 + i;
        if (n < N_NODES) {
            float4 av = (i == 0) ? a0 : a1;
            const unsigned short* hp = h_in + (size_t)n * HID + c0;
            float o0 = fmaxf(av.x + bv2.x, 0.f) + bf2f(hp[0]);
            float o1 = fmaxf(av.y + bv2.y, 0.f) + bf2f(hp[1]);
            float o2 = fmaxf(av.z + bv2.z, 0.f) + bf2f(hp[2]);
            float o3 = fmaxf(av.w + bv2.w, 0.f) + bf2f(hp[3]);
            uint2 pk;
            pk.x = (unsigned int)f2bf(o0) | ((unsigned int)f2bf(o1) << 16);
            pk.y = (unsigned int)f2bf(o2) | ((unsigned int)f2bf(o3) << 16);
            *(uint2*)(h_out + (size_t)n * HID + c0) = pk;
        }
    }
#undef GEMM_LDS
}

// ---------------- global add pool (bf16 h) ----------------
__global__ __launch_bounds__(256) void pool_kernel(
    const unsigned short* __restrict__ h, const int* __restrict__ batch,
    float* __restrict__ pooled) {
    int tid = threadIdx.x;
    int w = tid >> 6, j = tid & 63;
    int n0 = blockIdx.x * 256 + w * 64;
    if (n0 >= N_NODES) return;
    int nend = min(n0 + 64, N_NODES);
    float acc = 0.f;
    int cur = batch[n0];
    for (int n = n0; n < nend; n++) {
        int b = batch[n];
        if (b != cur) {
            atomicAdd(&pooled[cur * HID + j], acc);
            acc = 0.f;
            cur = b;
        }
        acc += bf2f(h[(size_t)n * HID + j]);
    }
    atomicAdd(&pooled[cur * HID + j], acc);
}

// ---------------- final FC ----------------
__global__ __launch_bounds__(256) void final_kernel(
    const float* __restrict__ pooled, const float* __restrict__ w_fc,
    const float* __restrict__ b_fc, float* __restrict__ out) {
    int gid = blockIdx.x * 256 + threadIdx.x;
    if (gid >= N_GRAPHS * LAT) return;
    int g = gid >> 5, j = gid & 31;
    float acc = b_fc[j];
#pragma unroll
    for (int k = 0; k < HID; k++)
        acc += pooled[g * HID + k] * w_fc[k * LAT + j];
    out[gid] = acc;
}

extern "C" void kernel_launch(void* const* d_in, const int* in_sizes, int n_in,
                              void* d_out, int out_size, void* d_ws,
                              size_t ws_size, hipStream_t stream) {
    const float* x     = (const float*)d_in[0];
    const int*   ei    = (const int*)d_in[1];
    const int*   batch = (const int*)d_in[2];
    const float* w_in  = (const float*)d_in[3];
    const float* b_in  = (const float*)d_in[4];
    const float* w1    = (const float*)d_in[5];
    const float* b1    = (const float*)d_in[6];
    const float* w2    = (const float*)d_in[7];
    const float* b2    = (const float*)d_in[8];
    const float* w_fc  = (const float*)d_in[9];
    const float* b_fc  = (const float*)d_in[10];
    float* out = (float*)d_out;

    // persistent: h0 | h1 (bf16, 12.8 MB each) | pooled | offsets | srcs (~30 MB)
    unsigned short* h0 = (unsigned short*)d_ws;
    unsigned short* h1 = h0 + (size_t)N_NODES * HID;
    float* pooled  = (float*)(h1 + (size_t)N_NODES * HID);
    int*   offsets = (int*)(pooled + N_GRAPHS * HID);   // N_NODES+1
    int*   srcs    = offsets + (N_NODES + 2);           // N_EDGES
    // CSR build scratch overlaid into h1 (dead before layer 0 writes h1)
    int* counts = (int*)h1;             // N_NODES
    int* cursor = counts + N_NODES;     // N_NODES
    int* bsums  = cursor + N_NODES;     // NB_SUM
    int* bofs   = bsums + (NB_SUM + 1); // NB_SUM

    proj_kernel<<<(N_NODES + 3) / 4, 256, 0, stream>>>(x, w_in, b_in, h0);

    // CSR build (once; edges constant across layers)
    hipMemsetAsync(counts, 0, N_NODES * sizeof(int), stream);
    hist_kernel<<<(N_EDGES + 255) / 256, 256, 0, stream>>>(ei, counts);
    block_sum_kernel<<<NB_SUM, 256, 0, stream>>>(counts, bsums);
    scan_bsums_kernel<<<1, 256, 0, stream>>>(bsums, bofs, NB_SUM);
    offsets_kernel<<<NB_SUM, 256, 0, stream>>>(counts, bofs, offsets, cursor);
    fill_kernel<<<(N_EDGES + 255) / 256, 256, 0, stream>>>(ei, cursor, srcs);

    // fused layers, h double-buffered: h0->h1->h0->h1
    const unsigned short* hin = h0;
    unsigned short* hout = h1;
    for (int i = 0; i < N_LAYERS; i++) {
        layer_kernel<<<(N_NODES + 63) / 64, 512, 0, stream>>>(
            hin, hout, offsets, srcs,
            w1 + (size_t)i * HID * HID, b1 + (size_t)i * HID,
            w2 + (size_t)i * HID * HID, b2 + (size_t)i * HID);
        const unsigned short* tmp = hout;
        hout = (unsigned short*)hin;
        hin = tmp;
    }

    hipMemsetAsync(pooled, 0, N_GRAPHS * HID * sizeof(float), stream);
    pool_kernel<<<(N_NODES + 255) / 256, 256, 0, stream>>>(hin, batch, pooled);
    final_kernel<<<(N_GRAPHS * LAT + 255) / 256, 256, 0, stream>>>(
        pooled, w_fc, b_fc, out);
}

// Round 7
// 525.467 us; speedup vs baseline: 1.0892x; 1.0114x over previous
//
#include <hip/hip_runtime.h>

#define N_NODES 100000
#define N_EDGES 1000000
#define N_GRAPHS 128
#define IN_DIM 32
#define HID 64
#define LAT 32
#define N_LAYERS 3

#define MPAD 68  // padded LDS row stride (floats), 16B-aligned rows
#define NB_SUM ((N_NODES + 255) / 256)  // 391 scan blocks

// bf16 <-> fp32 helpers (storage-only bf16; all math fp32)
__device__ __forceinline__ float bf2f(unsigned short u) {
    return __uint_as_float(((unsigned int)u) << 16);
}
__device__ __forceinline__ unsigned short f2bf(float f) {
    unsigned int x = __float_as_uint(f);
    x += 0x7fffu + ((x >> 16) & 1u);  // round-to-nearest-even
    return (unsigned short)(x >> 16);
}

// ---------------- input projection: h = bf16(x @ w_in + b_in) --------------
// also zeroes the CSR `counts` array (folds a memset dispatch)
__global__ __launch_bounds__(256) void proj_kernel(
    const float* __restrict__ x, const float* __restrict__ w_in,
    const float* __restrict__ b_in, unsigned short* __restrict__ h,
    int* __restrict__ counts) {
    __shared__ float ws[IN_DIM * HID];   // 8 KB
    __shared__ float xs[4 * IN_DIM];
    int tid = threadIdx.x;
    int gtid = blockIdx.x * 256 + tid;
    if (gtid < N_NODES) counts[gtid] = 0;
    for (int i = tid; i < IN_DIM * HID / 4; i += 256)
        ((float4*)ws)[i] = ((const float4*)w_in)[i];
    if (tid < 32) {
        int r = tid >> 3, c4 = tid & 7;
        int nn = blockIdx.x * 4 + r;
        float4 v = make_float4(0.f, 0.f, 0.f, 0.f);
        if (nn < N_NODES) v = ((const float4*)(x + (size_t)nn * IN_DIM))[c4];
        ((float4*)xs)[tid] = v;
    }
    __syncthreads();
    int w = tid >> 6, j = tid & 63;
    int n = blockIdx.x * 4 + w;
    if (n >= N_NODES) return;
    float acc = b_in[j];
#pragma unroll
    for (int k = 0; k < IN_DIM; k += 4) {
        float4 xv = *(const float4*)&xs[w * IN_DIM + k];
        acc += xv.x * ws[(k + 0) * HID + j];
        acc += xv.y * ws[(k + 1) * HID + j];
        acc += xv.z * ws[(k + 2) * HID + j];
        acc += xv.w * ws[(k + 3) * HID + j];
    }
    h[(size_t)n * HID + j] = f2bf(acc);
}

// ---------------- CSR build ----------------
// also zeroes `pooled` (folds a memset dispatch; pool runs much later)
__global__ __launch_bounds__(256) void hist_kernel(const int* __restrict__ ei,
                                                   int* __restrict__ counts,
                                                   float* __restrict__ pooled) {
    int e = blockIdx.x * 256 + threadIdx.x;
    if (e < N_GRAPHS * HID) pooled[e] = 0.f;
    if (e < N_EDGES) atomicAdd(&counts[ei[N_EDGES + e]], 1);
}

__global__ __launch_bounds__(256) void block_sum_kernel(
    const int* __restrict__ counts, int* __restrict__ bsums) {
    __shared__ int sd[4];
    int i = blockIdx.x * 256 + threadIdx.x;
    int v = (i < N_NODES) ? counts[i] : 0;
#pragma unroll
    for (int off = 32; off >= 1; off >>= 1) v += __shfl_down(v, off);
    int lane = threadIdx.x & 63, w = threadIdx.x >> 6;
    if (lane == 0) sd[w] = v;
    __syncthreads();
    if (threadIdx.x == 0) bsums[blockIdx.x] = sd[0] + sd[1] + sd[2] + sd[3];
}

__global__ __launch_bounds__(256) void scan_bsums_kernel(
    const int* __restrict__ bsums, int* __restrict__ bofs, int nb) {
    __shared__ int tmp[256];
    __shared__ int carry;
    int tid = threadIdx.x;
    if (tid == 0) carry = 0;
    __syncthreads();
    for (int base = 0; base < nb; base += 256) {
        int v = (base + tid < nb) ? bsums[base + tid] : 0;
        tmp[tid] = v;
        __syncthreads();
        for (int off = 1; off < 256; off <<= 1) {
            int t = (tid >= off) ? tmp[tid - off] : 0;
            __syncthreads();
            tmp[tid] += t;
            __syncthreads();
        }
        if (base + tid < nb) bofs[base + tid] = carry + tmp[tid] - v;
        __syncthreads();
        if (tid == 255) carry += tmp[255];
        __syncthreads();
    }
}

__global__ __launch_bounds__(256) void offsets_kernel(
    const int* __restrict__ counts, const int* __restrict__ bofs,
    int* __restrict__ offsets, int* __restrict__ cursor) {
    __shared__ int tmp[256];
    int tid = threadIdx.x;
    int i = blockIdx.x * 256 + tid;
    int v = (i < N_NODES) ? counts[i] : 0;
    tmp[tid] = v;
    __syncthreads();
    for (int off = 1; off < 256; off <<= 1) {
        int t = (tid >= off) ? tmp[tid - off] : 0;
        __syncthreads();
        tmp[tid] += t;
        __syncthreads();
    }
    int excl = tmp[tid] - v + bofs[blockIdx.x];
    if (i < N_NODES) {
        offsets[i] = excl;
        cursor[i] = excl;
        if (i == N_NODES - 1) offsets[N_NODES] = excl + v;
    }
}

// plain store (R5 lesson: nontemporal scatter bypasses L2 write-combining -> ~2x slower)
__global__ __launch_bounds__(256) void fill_kernel(const int* __restrict__ ei,
                                                   int* __restrict__ cursor,
                                                   int* __restrict__ srcs) {
    int e = blockIdx.x * 256 + threadIdx.x;
    if (e < N_EDGES) {
        int d = ei[N_EDGES + e];
        int p = atomicAdd(&cursor[d], 1);
        srcs[p] = ei[e];
    }
}

// ---------------- fused layer: gather + GIN MLP (bf16 h storage) -----------
// block = 64 nodes, 512 threads (8 waves). SINGLE 16 KB weight buffer:
// w1 staged before GEMM1; w2 preloaded to regs at kernel start and written
// to the same buffer after the post-GEMM1 barrier. LDS = 33.4 KB ->
// 4 blocks/CU = 32 waves (vs 3 blocks/49KB in R6) for gather latency hiding.
__global__ __launch_bounds__(512) void layer_kernel(
    const unsigned short* __restrict__ h_in, unsigned short* __restrict__ h_out,
    const int* __restrict__ offsets, const int* __restrict__ srcs,
    const float* __restrict__ w1, const float* __restrict__ b1,
    const float* __restrict__ w2, const float* __restrict__ b2) {
    __shared__ float ws[HID * HID];    // 16 KB, holds w1 then w2
    __shared__ float ms[64 * MPAD];    // 17.4 KB, m then t
    int tid = threadIdx.x;
    int row0 = blockIdx.x * 64;

    // stage w1 -> LDS; preload w2 -> regs (2 float4/thread, written later)
    float4 w1a = ((const float4*)w1)[tid * 2];
    float4 w1b = ((const float4*)w1)[tid * 2 + 1];
    float4 w2a = ((const float4*)w2)[tid * 2];
    float4 w2b = ((const float4*)w2)[tid * 2 + 1];
    ((float4*)ws)[tid * 2] = w1a;
    ((float4*)ws)[tid * 2 + 1] = w1b;

    // ---- gather phase: wave w rows [w*8,w*8+8); quarter-wave q = edge slot;
    // lane loads uint2 = 4 bf16 feats; 8 edges in flight/wave ----
    int w = tid >> 6, j = tid & 63;
    int q = j >> 4;          // edge slot 0..3
    int fl = j & 15;         // feature-quad index
#define UNPACK_ADD(A, V)                               \
    do {                                               \
        (A).x += __uint_as_float((V).x << 16);         \
        (A).y += __uint_as_float((V).x & 0xffff0000u); \
        (A).z += __uint_as_float((V).y << 16);         \
        (A).w += __uint_as_float((V).y & 0xffff0000u); \
    } while (0)

    for (int r = w * 8; r < w * 8 + 8; r++) {
        int n = row0 + r;
        float4 acc = make_float4(0.f, 0.f, 0.f, 0.f), acc2 = acc;
        if (n < N_NODES) {
            int beg = offsets[n], end = offsets[n + 1];
            for (int c = beg; c < end; c += 64) {
                int myS = (c + j < end) ? srcs[c + j] : 0;
                int m = min(64, end - c);
                int i2 = 0;
                for (; i2 + 7 < m; i2 += 8) {
                    int sA = __shfl(myS, i2 + q);
                    int sB = __shfl(myS, i2 + 4 + q);
                    uint2 va = *(const uint2*)(h_in + (size_t)sA * HID + (fl << 2));
                    uint2 vb = *(const uint2*)(h_in + (size_t)sB * HID + (fl << 2));
                    UNPACK_ADD(acc, va);
                    UNPACK_ADD(acc2, vb);
                }
                for (; i2 < m; i2 += 4) {
                    int idx = i2 + q;
                    if (idx < m) {
                        int s = __shfl(myS, idx);
                        uint2 v = *(const uint2*)(h_in + (size_t)s * HID + (fl << 2));
                        UNPACK_ADD(acc, v);
                    }
                }
            }
            if (q == 0) {  // self term: m = agg + h (eps=0)
                uint2 v = *(const uint2*)(h_in + (size_t)n * HID + (fl << 2));
                UNPACK_ADD(acc, v);
            }
        }
        acc.x += acc2.x; acc.y += acc2.y; acc.z += acc2.z; acc.w += acc2.w;
        acc.x += __shfl_xor(acc.x, 16); acc.y += __shfl_xor(acc.y, 16);
        acc.z += __shfl_xor(acc.z, 16); acc.w += __shfl_xor(acc.w, 16);
        acc.x += __shfl_xor(acc.x, 32); acc.y += __shfl_xor(acc.y, 32);
        acc.z += __shfl_xor(acc.z, 32); acc.w += __shfl_xor(acc.w, 32);
        if (q == 0) *(float4*)&ms[r * MPAD + (fl << 2)] = acc;
    }
#undef UNPACK_ADD
    __syncthreads();  // #1: ms(m) and ws(w1) visible

    // ---- GEMM phase: ty 0..31 (2 rows), tx 0..15 (4 cols) ----
    int ty = tid >> 4, tx = tid & 15;
    int r0 = ty * 2, c0 = tx * 4;

    float4 a0, a1;
#define GEMM_LDS()                                                            \
    do {                                                                      \
        a0 = make_float4(0.f, 0.f, 0.f, 0.f); a1 = a0;                        \
        _Pragma("unroll 4")                                                   \
        for (int k0 = 0; k0 < HID; k0 += 4) {                                 \
            float4 m0 = *(const float4*)&ms[(r0 + 0) * MPAD + k0];            \
            float4 m1 = *(const float4*)&ms[(r0 + 1) * MPAD + k0];            \
            float4 w0 = *(const float4*)&ws[(k0 + 0) * HID + c0];             \
            float4 w1v = *(const float4*)&ws[(k0 + 1) * HID + c0];            \
            float4 w2v = *(const float4*)&ws[(k0 + 2) * HID + c0];            \
            float4 w3v = *(const float4*)&ws[(k0 + 3) * HID + c0];            \
            a0.x += m0.x * w0.x + m0.y * w1v.x + m0.z * w2v.x + m0.w * w3v.x; \
            a0.y += m0.x * w0.y + m0.y * w1v.y + m0.z * w2v.y + m0.w * w3v.y; \
            a0.z += m0.x * w0.z + m0.y * w1v.z + m0.z * w2v.z + m0.w * w3v.z; \
            a0.w += m0.x * w0.w + m0.y * w1v.w + m0.z * w2v.w + m0.w * w3v.w; \
            a1.x += m1.x * w0.x + m1.y * w1v.x + m1.z * w2v.x + m1.w * w3v.x; \
            a1.y += m1.x * w0.y + m1.y * w1v.y + m1.z * w2v.y + m1.w * w3v.y; \
            a1.z += m1.x * w0.z + m1.y * w1v.z + m1.z * w2v.z + m1.w * w3v.z; \
            a1.w += m1.x * w0.w + m1.y * w1v.w + m1.z * w2v.w + m1.w * w3v.w; \
        }                                                                     \
    } while (0)

    GEMM_LDS();  // GEMM1 (ws = w1)

    float4 bv1 = *(const float4*)&b1[c0];
    float4 t0 = make_float4(fmaxf(a0.x + bv1.x, 0.f), fmaxf(a0.y + bv1.y, 0.f),
                            fmaxf(a0.z + bv1.z, 0.f), fmaxf(a0.w + bv1.w, 0.f));
    float4 t1 = make_float4(fmaxf(a1.x + bv1.x, 0.f), fmaxf(a1.y + bv1.y, 0.f),
                            fmaxf(a1.z + bv1.z, 0.f), fmaxf(a1.w + bv1.w, 0.f));

    __syncthreads();  // #2: all GEMM1 reads of ms AND ws complete
    *(float4*)&ms[(r0 + 0) * MPAD + c0] = t0;
    *(float4*)&ms[(r0 + 1) * MPAD + c0] = t1;
    ((float4*)ws)[tid * 2] = w2a;       // overwrite ws with w2
    ((float4*)ws)[tid * 2 + 1] = w2b;
    __syncthreads();  // #3: ms(t) and ws(w2) visible

    GEMM_LDS();  // GEMM2 (ws = w2)

    float4 bv2 = *(const float4*)&b2[c0];
#pragma unroll
    for (int i = 0; i < 2; i++) {
        int n = row0 + r0 + i;
        if (n < N_NODES) {
            float4 av = (i == 0) ? a0 : a1;
            const unsigned short* hp = h_in + (size_t)n * HID + c0;
            float o0 = fmaxf(av.x + bv2.x, 0.f) + bf2f(hp[0]);
            float o1 = fmaxf(av.y + bv2.y, 0.f) + bf2f(hp[1]);
            float o2 = fmaxf(av.z + bv2.z, 0.f) + bf2f(hp[2]);
            float o3 = fmaxf(av.w + bv2.w, 0.f) + bf2f(hp[3]);
            uint2 pk;
            pk.x = (unsigned int)f2bf(o0) | ((unsigned int)f2bf(o1) << 16);
            pk.y = (unsigned int)f2bf(o2) | ((unsigned int)f2bf(o3) << 16);
            *(uint2*)(h_out + (size_t)n * HID + c0) = pk;
        }
    }
#undef GEMM_LDS
}

// ---------------- global add pool (bf16 h) ----------------
__global__ __launch_bounds__(256) void pool_kernel(
    const unsigned short* __restrict__ h, const int* __restrict__ batch,
    float* __restrict__ pooled) {
    int tid = threadIdx.x;
    int w = tid >> 6, j = tid & 63;
    int n0 = blockIdx.x * 256 + w * 64;
    if (n0 >= N_NODES) return;
    int nend = min(n0 + 64, N_NODES);
    float acc = 0.f;
    int cur = batch[n0];
    for (int n = n0; n < nend; n++) {
        int b = batch[n];
        if (b != cur) {
            atomicAdd(&pooled[cur * HID + j], acc);
            acc = 0.f;
            cur = b;
        }
        acc += bf2f(h[(size_t)n * HID + j]);
    }
    atomicAdd(&pooled[cur * HID + j], acc);
}

// ---------------- final FC ----------------
__global__ __launch_bounds__(256) void final_kernel(
    const float* __restrict__ pooled, const float* __restrict__ w_fc,
    const float* __restrict__ b_fc, float* __restrict__ out) {
    int gid = blockIdx.x * 256 + threadIdx.x;
    if (gid >= N_GRAPHS * LAT) return;
    int g = gid >> 5, j = gid & 31;
    float acc = b_fc[j];
#pragma unroll
    for (int k = 0; k < HID; k++)
        acc += pooled[g * HID + k] * w_fc[k * LAT + j];
    out[gid] = acc;
}

extern "C" void kernel_launch(void* const* d_in, const int* in_sizes, int n_in,
                              void* d_out, int out_size, void* d_ws,
                              size_t ws_size, hipStream_t stream) {
    const float* x     = (const float*)d_in[0];
    const int*   ei    = (const int*)d_in[1];
    const int*   batch = (const int*)d_in[2];
    const float* w_in  = (const float*)d_in[3];
    const float* b_in  = (const float*)d_in[4];
    const float* w1    = (const float*)d_in[5];
    const float* b1    = (const float*)d_in[6];
    const float* w2    = (const float*)d_in[7];
    const float* b2    = (const float*)d_in[8];
    const float* w_fc  = (const float*)d_in[9];
    const float* b_fc  = (const float*)d_in[10];
    float* out = (float*)d_out;

    // persistent: h0 | h1 (bf16, 12.8 MB each) | pooled | offsets | srcs (~30 MB)
    unsigned short* h0 = (unsigned short*)d_ws;
    unsigned short* h1 = h0 + (size_t)N_NODES * HID;
    float* pooled  = (float*)(h1 + (size_t)N_NODES * HID);
    int*   offsets = (int*)(pooled + N_GRAPHS * HID);   // N_NODES+1
    int*   srcs    = offsets + (N_NODES + 2);           // N_EDGES
    // CSR build scratch overlaid into h1 (dead before layer 0 writes h1)
    int* counts = (int*)h1;             // N_NODES
    int* cursor = counts + N_NODES;     // N_NODES
    int* bsums  = cursor + N_NODES;     // NB_SUM
    int* bofs   = bsums + (NB_SUM + 1); // NB_SUM

    proj_kernel<<<(N_NODES + 3) / 4, 256, 0, stream>>>(x, w_in, b_in, h0, counts);

    // CSR build (once; edges constant across layers)
    hist_kernel<<<(N_EDGES + 255) / 256, 256, 0, stream>>>(ei, counts, pooled);
    block_sum_kernel<<<NB_SUM, 256, 0, stream>>>(counts, bsums);
    scan_bsums_kernel<<<1, 256, 0, stream>>>(bsums, bofs, NB_SUM);
    offsets_kernel<<<NB_SUM, 256, 0, stream>>>(counts, bofs, offsets, cursor);
    fill_kernel<<<(N_EDGES + 255) / 256, 256, 0, stream>>>(ei, cursor, srcs);

    // fused layers, h double-buffered: h0->h1->h0->h1
    const unsigned short* hin = h0;
    unsigned short* hout = h1;
    for (int i = 0; i < N_LAYERS; i++) {
        layer_kernel<<<(N_NODES + 63) / 64, 512, 0, stream>>>(
            hin, hout, offsets, srcs,
            w1 + (size_t)i * HID * HID, b1 + (size_t)i * HID,
            w2 + (size_t)i * HID * HID, b2 + (size_t)i * HID);
        const unsigned short* tmp = hout;
        hout = (unsigned short*)hin;
        hin = tmp;
    }

    pool_kernel<<<(N_NODES + 255) / 256, 256, 0, stream>>>(hin, batch, pooled);
    final_kernel<<<(N_GRAPHS * LAT + 255) / 256, 256, 0, stream>>>(
        pooled, w_fc, b_fc, out);
}